// Round 4
// baseline (76.082 us; speedup 1.0000x reference)
//
#include <hip/hip_runtime.h>
#include <cstdint>
#include <cstddef>

// HarmonicSynth, single plain-launch kernel with producer/consumer chunk totals.
// y[b,n] = sum_h amp[b,n,h] * sin(Omega[b,n]*(h+1) + phase[b,h]),
// Omega = inclusive prefix over n of (2pi/48000)*f0; phase_out = harmonics of
// Omega[N-1] mod 2pi. Double scan (numpy f64 reference), f32 harmonic sins.
//
// Cross-block dependency handled WITHOUT grid sync: csum[] zeroed on-stream,
// each block release-stores its chunk total (always >= ~8.0, so != 0.0), and
// wave 0 of each block spin-loads its <=124 same-batch predecessors.
// Deadlock-free by construction: __launch_bounds__(256,4) caps VGPR at 128 ->
// 4 blocks/CU guaranteed -> all 1000 blocks co-resident (capacity 1024).

#define B   8
#define N   96000
#define H   64
#define CH  768          // samples per chunk (divides N)
#define NCH 125          // N / CH
#define G   3            // CH / 256
#define PF  4            // amp float4 prefetches issued before the scan/spin

static_assert(CH * NCH == N, "chunking");
static_assert(G * 256 == CH, "scan layout");
static_assert(NCH <= 128, "predecessor spin uses 2 loads/lane");

static constexpr double TWO_PI_D     = 6.2831853071795864769252867665590057684;
static constexpr double INV_TWO_PI_D = 1.0 / TWO_PI_D;
static constexpr double OMEGA_D      = TWO_PI_D / 48000.0;

__device__ __forceinline__ float wrap2pi_f(double v) {
  double r = v - TWO_PI_D * floor(v * INV_TWO_PI_D);
  return (float)r;   // [0, 2pi); sin periodic so edge rounding harmless
}

__global__ __launch_bounds__(256, 4) void k_fused(const float* __restrict__ f0,
                                                  const float* __restrict__ amp,
                                                  const float* __restrict__ phase,
                                                  double* __restrict__ csum,
                                                  float* __restrict__ out) {
  const int blk = blockIdx.x;
  const int b = blk / NCH, c = blk - b * NCH;
  const int tid = threadIdx.x;
  const int lane = tid & 63, wv = tid >> 6;
  const size_t base = (size_t)b * N + (size_t)c * CH;

  __shared__ float  s_w[CH];      // per-sample Omega mod 2pi (f32 radians)
  __shared__ double s_warp[4];
  __shared__ double s_pre;        // sum of predecessor chunk totals
  __shared__ double s_last;       // full-precision Omega at last sample of chunk

  // --- f0 loads for the block scan (single read of f0) ---------------------
  const float* f0p = f0 + base;
  const float f0v0 = f0p[tid * G + 0];
  const float f0v1 = f0p[tid * G + 1];
  const float f0v2 = f0p[tid * G + 2];

  // --- amp prefetches for the first PF synthesis iterations ----------------
  const int hq = lane & 15;            // harmonic quad 0..15
  const int sl = lane >> 4;            // sample slot within wave 0..3
  const float4* ampb = reinterpret_cast<const float4*>(amp) + base * (H / 4);
  float4 pf[PF];
#pragma unroll
  for (int j = 0; j < PF; ++j) {
    const int nl = j * 16 + (wv << 2) + sl;
    pf[j] = ampb[(size_t)nl * (H / 4) + hq];
  }

  // --- in-block double scan ------------------------------------------------
  const double l0 = OMEGA_D * (double)f0v0;
  const double l1 = OMEGA_D * (double)f0v1;
  const double l2 = OMEGA_D * (double)f0v2;
  const double ts = l0 + l1 + l2;

  double x = ts;
#pragma unroll
  for (int off = 1; off < 64; off <<= 1) {
    double y = __shfl_up(x, off);
    if (lane >= off) x += y;
  }
  if (lane == 63) s_warp[wv] = x;      // wave-inclusive totals
  __syncthreads();
  if (tid == 0) {
    double a = 0.0;
#pragma unroll
    for (int w = 0; w < 4; ++w) { double t = s_warp[w]; s_warp[w] = a; a += t; }
    // publish this block's chunk total (device-visible release; value >= ~8)
    __hip_atomic_store(&csum[blk], a, __ATOMIC_RELEASE, __HIP_MEMORY_SCOPE_AGENT);
  }
  __syncthreads();

  // --- wave 0: spin until <=124 same-batch predecessors published ----------
  if (wv == 0) {
    const double* cs = csum + b * NCH;
    const bool need0 = (lane < c);
    const bool need1 = (lane + 64 < c);
    double v0 = 0.0, v1 = 0.0;
    for (;;) {
      if (need0 && v0 == 0.0)
        v0 = __hip_atomic_load(&cs[lane], __ATOMIC_ACQUIRE,
                               __HIP_MEMORY_SCOPE_AGENT);
      if (need1 && v1 == 0.0)
        v1 = __hip_atomic_load(&cs[lane + 64], __ATOMIC_ACQUIRE,
                               __HIP_MEMORY_SCOPE_AGENT);
      const int done = ((!need0) | (v0 != 0.0)) & ((!need1) | (v1 != 0.0));
      if (__all(done)) break;
      __builtin_amdgcn_s_sleep(2);
    }
    double pre = v0 + v1;
    for (int off = 32; off > 0; off >>= 1) pre += __shfl_xor(pre, off);
    if (lane == 0) s_pre = pre;
  }
  __syncthreads();

  const double run = s_pre + s_warp[wv] + (x - ts);  // exclusive prefix
  const double o0 = run + l0;
  const double o1 = o0 + l1;
  const double o2 = o1 + l2;
  s_w[tid * G + 0] = wrap2pi_f(o0);
  s_w[tid * G + 1] = wrap2pi_f(o1);
  s_w[tid * G + 2] = wrap2pi_f(o2);
  if (tid == 255) s_last = o2;
  __syncthreads();

  // --- synthesis: wave = 4 samples x (16 lanes x 4 harmonics) --------------
  const float m0 = (float)(hq * 4 + 1), m1 = (float)(hq * 4 + 2);
  const float m2 = (float)(hq * 4 + 3), m3 = (float)(hq * 4 + 4);
  const float* phb = phase + b * H;
  const float p0 = phb[hq * 4 + 0], p1 = phb[hq * 4 + 1];
  const float p2 = phb[hq * 4 + 2], p3 = phb[hq * 4 + 3];
  float* yb = out + base;

  // first PF iterations consume the prefetched values
#pragma unroll
  for (int j = 0; j < PF; ++j) {
    const int nl = j * 16 + (wv << 2) + sl;
    const float w = s_w[nl];
    const float4 a4 = pf[j];
    float acc;
    acc  = a4.x * __sinf(fmaf(w, m0, p0));
    acc += a4.y * __sinf(fmaf(w, m1, p1));
    acc += a4.z * __sinf(fmaf(w, m2, p2));
    acc += a4.w * __sinf(fmaf(w, m3, p3));
    acc += __shfl_xor(acc, 1);
    acc += __shfl_xor(acc, 2);
    acc += __shfl_xor(acc, 4);
    acc += __shfl_xor(acc, 8);
    if (hq == 0) yb[nl] = acc;
  }

#pragma unroll 4
  for (int i0 = PF * 16; i0 < CH; i0 += 16) {
    const int nl = i0 + (wv << 2) + sl;
    const float w = s_w[nl];
    const float4 a4 = ampb[(size_t)nl * (H / 4) + hq];
    float acc;
    acc  = a4.x * __sinf(fmaf(w, m0, p0));
    acc += a4.y * __sinf(fmaf(w, m1, p1));
    acc += a4.z * __sinf(fmaf(w, m2, p2));
    acc += a4.w * __sinf(fmaf(w, m3, p3));
    acc += __shfl_xor(acc, 1);
    acc += __shfl_xor(acc, 2);
    acc += __shfl_xor(acc, 4);
    acc += __shfl_xor(acc, 8);
    if (hq == 0) yb[nl] = acc;
  }

  // --- phase_out from the last chunk (double remainder) --------------------
  if (c == NCH - 1 && tid < H) {
    const double arg = s_last * (double)(tid + 1) + (double)phase[b * H + tid];
    double r = arg - TWO_PI_D * floor(arg * INV_TWO_PI_D);
    if (r < 0.0) r += TWO_PI_D;
    if (r >= TWO_PI_D) r -= TWO_PI_D;
    out[(size_t)B * N + b * H + tid] = (float)r;
  }
}

extern "C" void kernel_launch(void* const* d_in, const int* in_sizes, int n_in,
                              void* d_out, int out_size, void* d_ws, size_t ws_size,
                              hipStream_t stream) {
  const float* f0    = (const float*)d_in[0];   // (B, N)
  const float* amp   = (const float*)d_in[1];   // (B, N, H)
  const float* phase = (const float*)d_in[2];   // (B, H)
  float* out = (float*)d_out;                   // y (B*N) ++ phase_out (B*H)
  double* csum = (double*)d_ws;                 // B*NCH doubles = 8000 B

  // 0.0 == "not yet published"; true chunk totals are >= ~8.0
  hipMemsetAsync(d_ws, 0, (size_t)B * NCH * sizeof(double), stream);
  k_fused<<<B * NCH, 256, 0, stream>>>(f0, amp, phase, csum, out);
}

// Round 5
// 45.021 us; speedup vs baseline: 1.6899x; 1.6899x over previous
//
#include <hip/hip_runtime.h>
#include <cstdint>
#include <cstddef>

// HarmonicSynth, single plain-launch kernel with producer/consumer chunk totals.
// y[b,n] = sum_h amp[b,n,h] * sin(Omega[b,n]*(h+1) + phase[b,h]),
// Omega = inclusive prefix over n of (2pi/48000)*f0; phase_out = harmonics of
// Omega[N-1] mod 2pi. Double scan (numpy f64 reference), f32 harmonic sins.
//
// Cross-block dependency: csum[] zeroed on-stream; each block publishes its
// chunk total with a RELAXED agent-scope atomic store (value >= ~8.0, so 0.0
// means "not yet"); wave 0 of each block spin-loads predecessors with RELAXED
// agent-scope atomic loads. RELAXED, not acq/rel: the payload IS the atomic
// value, no other memory is transferred, and acquire loads in a spin loop emit
// per-iteration L2 invalidates on gfx950 that evict the streaming amp lines
// (R4 post-mortem: 128us dispatches at 1.6 TB/s effective).
// Deadlock-free: __launch_bounds__(256,4) -> 4 blocks/CU -> 1024 resident >= 1000.

#define B   8
#define N   96000
#define H   64
#define CH  768          // samples per chunk (divides N)
#define NCH 125          // N / CH
#define G   3            // CH / 256
#define PF  8            // amp float4 prefetches issued before the scan/spin

static_assert(CH * NCH == N, "chunking");
static_assert(G * 256 == CH, "scan layout");
static_assert(NCH <= 128, "predecessor spin uses 2 loads/lane");

static constexpr double TWO_PI_D     = 6.2831853071795864769252867665590057684;
static constexpr double INV_TWO_PI_D = 1.0 / TWO_PI_D;
static constexpr double OMEGA_D      = TWO_PI_D / 48000.0;

__device__ __forceinline__ float wrap2pi_f(double v) {
  double r = v - TWO_PI_D * floor(v * INV_TWO_PI_D);
  return (float)r;   // [0, 2pi); sin periodic so edge rounding harmless
}

__global__ __launch_bounds__(256, 4) void k_fused(const float* __restrict__ f0,
                                                  const float* __restrict__ amp,
                                                  const float* __restrict__ phase,
                                                  double* __restrict__ csum,
                                                  float* __restrict__ out) {
  const int blk = blockIdx.x;
  const int b = blk / NCH, c = blk - b * NCH;
  const int tid = threadIdx.x;
  const int lane = tid & 63, wv = tid >> 6;
  const size_t base = (size_t)b * N + (size_t)c * CH;

  __shared__ float  s_w[CH];      // per-sample Omega mod 2pi (f32 radians)
  __shared__ double s_warp[4];
  __shared__ double s_pre;        // sum of predecessor chunk totals
  __shared__ double s_last;       // full-precision Omega at last sample of chunk

  // --- f0 loads for the block scan (single read of f0) ---------------------
  const float* f0p = f0 + base;
  const float f0v0 = f0p[tid * G + 0];
  const float f0v1 = f0p[tid * G + 1];
  const float f0v2 = f0p[tid * G + 2];

  // --- amp prefetches for the first PF synthesis iterations ----------------
  const int hq = lane & 15;            // harmonic quad 0..15
  const int sl = lane >> 4;            // sample slot within wave 0..3
  const float4* ampb = reinterpret_cast<const float4*>(amp) + base * (H / 4);
  float4 pf[PF];
#pragma unroll
  for (int j = 0; j < PF; ++j) {
    const int nl = j * 16 + (wv << 2) + sl;
    pf[j] = ampb[(size_t)nl * (H / 4) + hq];
  }

  // --- in-block double scan ------------------------------------------------
  const double l0 = OMEGA_D * (double)f0v0;
  const double l1 = OMEGA_D * (double)f0v1;
  const double l2 = OMEGA_D * (double)f0v2;
  const double ts = l0 + l1 + l2;

  double x = ts;
#pragma unroll
  for (int off = 1; off < 64; off <<= 1) {
    double y = __shfl_up(x, off);
    if (lane >= off) x += y;
  }
  if (lane == 63) s_warp[wv] = x;      // wave-inclusive totals
  __syncthreads();
  if (tid == 0) {
    double a = 0.0;
#pragma unroll
    for (int w = 0; w < 4; ++w) { double t = s_warp[w]; s_warp[w] = a; a += t; }
    // publish this block's chunk total; RELAXED: the value is the payload
    __hip_atomic_store(&csum[blk], a, __ATOMIC_RELAXED, __HIP_MEMORY_SCOPE_AGENT);
  }
  __syncthreads();

  // --- wave 0: spin until <=124 same-batch predecessors published ----------
  if (wv == 0) {
    const double* cs = csum + b * NCH;
    const bool need0 = (lane < c);
    const bool need1 = (lane + 64 < c);
    double v0 = 0.0, v1 = 0.0;
    for (;;) {
      if (need0 && v0 == 0.0)
        v0 = __hip_atomic_load(&cs[lane], __ATOMIC_RELAXED,
                               __HIP_MEMORY_SCOPE_AGENT);
      if (need1 && v1 == 0.0)
        v1 = __hip_atomic_load(&cs[lane + 64], __ATOMIC_RELAXED,
                               __HIP_MEMORY_SCOPE_AGENT);
      const int done = ((!need0) | (v0 != 0.0)) & ((!need1) | (v1 != 0.0));
      if (__all(done)) break;
      __builtin_amdgcn_s_sleep(2);
    }
    double pre = v0 + v1;
    for (int off = 32; off > 0; off >>= 1) pre += __shfl_xor(pre, off);
    if (lane == 0) s_pre = pre;
  }
  __syncthreads();

  const double run = s_pre + s_warp[wv] + (x - ts);  // exclusive prefix
  const double o0 = run + l0;
  const double o1 = o0 + l1;
  const double o2 = o1 + l2;
  s_w[tid * G + 0] = wrap2pi_f(o0);
  s_w[tid * G + 1] = wrap2pi_f(o1);
  s_w[tid * G + 2] = wrap2pi_f(o2);
  if (tid == 255) s_last = o2;
  __syncthreads();

  // --- synthesis: wave = 4 samples x (16 lanes x 4 harmonics) --------------
  const float m0 = (float)(hq * 4 + 1), m1 = (float)(hq * 4 + 2);
  const float m2 = (float)(hq * 4 + 3), m3 = (float)(hq * 4 + 4);
  const float* phb = phase + b * H;
  const float p0 = phb[hq * 4 + 0], p1 = phb[hq * 4 + 1];
  const float p2 = phb[hq * 4 + 2], p3 = phb[hq * 4 + 3];
  float* yb = out + base;

  // first PF iterations consume the prefetched values
#pragma unroll
  for (int j = 0; j < PF; ++j) {
    const int nl = j * 16 + (wv << 2) + sl;
    const float w = s_w[nl];
    const float4 a4 = pf[j];
    float acc;
    acc  = a4.x * __sinf(fmaf(w, m0, p0));
    acc += a4.y * __sinf(fmaf(w, m1, p1));
    acc += a4.z * __sinf(fmaf(w, m2, p2));
    acc += a4.w * __sinf(fmaf(w, m3, p3));
    acc += __shfl_xor(acc, 1);
    acc += __shfl_xor(acc, 2);
    acc += __shfl_xor(acc, 4);
    acc += __shfl_xor(acc, 8);
    if (hq == 0) yb[nl] = acc;
  }

#pragma unroll 4
  for (int i0 = PF * 16; i0 < CH; i0 += 16) {
    const int nl = i0 + (wv << 2) + sl;
    const float w = s_w[nl];
    const float4 a4 = ampb[(size_t)nl * (H / 4) + hq];
    float acc;
    acc  = a4.x * __sinf(fmaf(w, m0, p0));
    acc += a4.y * __sinf(fmaf(w, m1, p1));
    acc += a4.z * __sinf(fmaf(w, m2, p2));
    acc += a4.w * __sinf(fmaf(w, m3, p3));
    acc += __shfl_xor(acc, 1);
    acc += __shfl_xor(acc, 2);
    acc += __shfl_xor(acc, 4);
    acc += __shfl_xor(acc, 8);
    if (hq == 0) yb[nl] = acc;
  }

  // --- phase_out from the last chunk (double remainder) --------------------
  if (c == NCH - 1 && tid < H) {
    const double arg = s_last * (double)(tid + 1) + (double)phase[b * H + tid];
    double r = arg - TWO_PI_D * floor(arg * INV_TWO_PI_D);
    if (r < 0.0) r += TWO_PI_D;
    if (r >= TWO_PI_D) r -= TWO_PI_D;
    out[(size_t)B * N + b * H + tid] = (float)r;
  }
}

extern "C" void kernel_launch(void* const* d_in, const int* in_sizes, int n_in,
                              void* d_out, int out_size, void* d_ws, size_t ws_size,
                              hipStream_t stream) {
  const float* f0    = (const float*)d_in[0];   // (B, N)
  const float* amp   = (const float*)d_in[1];   // (B, N, H)
  const float* phase = (const float*)d_in[2];   // (B, H)
  float* out = (float*)d_out;                   // y (B*N) ++ phase_out (B*H)
  double* csum = (double*)d_ws;                 // B*NCH doubles = 8000 B

  // 0.0 == "not yet published"; true chunk totals are >= ~8.0
  hipMemsetAsync(d_ws, 0, (size_t)B * NCH * sizeof(double), stream);
  k_fused<<<B * NCH, 256, 0, stream>>>(f0, amp, phase, csum, out);
}

// Round 6
// 39.212 us; speedup vs baseline: 1.9403x; 1.1481x over previous
//
#include <hip/hip_runtime.h>
#include <cstdint>
#include <cstddef>

// HarmonicSynth, two-kernel structure (R2 base — fused/spin variants measured
// slower). y[b,n] = sum_h amp[b,n,h]*sin(Omega[b,n]*(h+1)+phase[b,h]);
// Omega = inclusive prefix of (2pi/48000)*f0; phase_out = Omega[N-1] harmonics
// mod 2pi. Double scan (numpy f64 ref), f32 harmonic sins.
//
// R5 post-mortem: timed replays are L3-resident (FETCH_SIZE ~3MB) -> limiter is
// latency hiding, not HBM BW. k_main: 384 thr/block (G=2) -> 6000 waves (73% of
// machine) vs 4000 (49%) at 256 thr. launch_bounds(384,6) caps VGPR ~84 so all
// blocks stay resident.

#define B   8
#define N   96000
#define H   64
#define CH  768          // samples per chunk (divides N)
#define NCH 125          // N / CH
#define TM  384          // k_main threads (6 waves)
#define GM  2            // samples per k_main thread: TM*GM == CH
#define NWV 6            // waves per k_main block
#define PF  4            // amp float4 prefetches before the scan

static_assert(CH * NCH == N, "chunking");
static_assert(TM * GM == CH, "main scan layout");
static_assert(NCH <= 128, "predecessor sum uses 2 loads/lane");

static constexpr double TWO_PI_D     = 6.2831853071795864769252867665590057684;
static constexpr double INV_TWO_PI_D = 1.0 / TWO_PI_D;
static constexpr double OMEGA_D      = TWO_PI_D / 48000.0;

__device__ __forceinline__ float wrap2pi_f(double v) {
  double r = v - TWO_PI_D * floor(v * INV_TWO_PI_D);
  return (float)r;   // [0, 2pi); sin periodic so edge rounding harmless
}

// ---- Kernel 1: per-chunk sums of omega (double) --------------------------
__global__ __launch_bounds__(256) void k_chunk_sums(const float* __restrict__ f0,
                                                    double* __restrict__ csum) {
  const int blk = blockIdx.x;              // b*NCH + c
  const int b = blk / NCH, c = blk - b * NCH;
  const float* p = f0 + (size_t)b * N + (size_t)c * CH;
  const int tid = threadIdx.x;

  double s = 0.0;
#pragma unroll
  for (int j = 0; j < 3; ++j) s += OMEGA_D * (double)p[tid + j * 256];

  for (int off = 32; off > 0; off >>= 1) s += __shfl_down(s, off);

  __shared__ double sw[4];
  const int lane = tid & 63, wv = tid >> 6;
  if (lane == 0) sw[wv] = s;
  __syncthreads();
  if (tid == 0) csum[blk] = sw[0] + sw[1] + sw[2] + sw[3];
}

// ---- Kernel 2: main — predecessor sum + in-block scan + synthesis --------
__global__ __launch_bounds__(TM, 6) void k_main(const float* __restrict__ f0,
                                                const float* __restrict__ amp,
                                                const float* __restrict__ phase,
                                                const double* __restrict__ csum,
                                                float* __restrict__ out) {
  const int blk = blockIdx.x;
  const int b = blk / NCH, c = blk - b * NCH;
  const int tid = threadIdx.x;
  const int lane = tid & 63, wv = tid >> 6;
  const size_t base = (size_t)b * N + (size_t)c * CH;

  __shared__ float  s_w[CH];      // per-sample Omega mod 2pi (f32 radians)
  __shared__ double s_warp[NWV];
  __shared__ double s_pre;        // sum of predecessor chunk totals
  __shared__ double s_last;       // full-precision Omega at last sample of chunk

  // --- f0 loads for the block scan (float2 vectorized) ---------------------
  const float2 f0v = reinterpret_cast<const float2*>(f0 + base)[tid];

  // --- amp prefetches for the first PF synthesis iterations ----------------
  const int hq = lane & 15;            // harmonic quad 0..15
  const int sl = lane >> 4;            // sample slot within wave 0..3
  const float4* ampb = reinterpret_cast<const float4*>(amp) + base * (H / 4);
  float4 pf[PF];
#pragma unroll
  for (int j = 0; j < PF; ++j) {
    const int nl = j * 24 + (wv << 2) + sl;
    pf[j] = ampb[(size_t)nl * (H / 4) + hq];
  }

  // --- wave 0: predecessor-chunk prefix (c <= 124, two loads/lane) ---------
  if (wv == 0) {
    double pre = 0.0;
    if (lane < c)      pre  = csum[b * NCH + lane];
    if (lane + 64 < c) pre += csum[b * NCH + lane + 64];
    for (int off = 32; off > 0; off >>= 1) pre += __shfl_xor(pre, off);
    if (lane == 0) s_pre = pre;
  }

  // --- in-block double scan (G=2 per thread) -------------------------------
  const double l0 = OMEGA_D * (double)f0v.x;
  const double l1 = OMEGA_D * (double)f0v.y;
  const double ts = l0 + l1;

  double x = ts;
#pragma unroll
  for (int off = 1; off < 64; off <<= 1) {
    double y = __shfl_up(x, off);
    if (lane >= off) x += y;
  }
  if (lane == 63) s_warp[wv] = x;      // wave-inclusive totals
  __syncthreads();
  if (tid == 0) {
    double a = 0.0;
#pragma unroll
    for (int w = 0; w < NWV; ++w) { double t = s_warp[w]; s_warp[w] = a; a += t; }
  }
  __syncthreads();

  const double run = s_pre + s_warp[wv] + (x - ts);  // exclusive prefix
  const double o0 = run + l0;
  const double o1 = o0 + l1;
  s_w[tid * GM + 0] = wrap2pi_f(o0);
  s_w[tid * GM + 1] = wrap2pi_f(o1);
  if (tid == TM - 1) s_last = o1;
  __syncthreads();

  // --- synthesis: wave = 4 samples x (16 lanes x 4 harmonics); 6 waves -----
  const float m0 = (float)(hq * 4 + 1), m1 = (float)(hq * 4 + 2);
  const float m2 = (float)(hq * 4 + 3), m3 = (float)(hq * 4 + 4);
  const float* phb = phase + b * H;
  const float p0 = phb[hq * 4 + 0], p1 = phb[hq * 4 + 1];
  const float p2 = phb[hq * 4 + 2], p3 = phb[hq * 4 + 3];
  float* yb = out + base;

  // first PF groups consume the prefetched values
#pragma unroll
  for (int j = 0; j < PF; ++j) {
    const int nl = j * 24 + (wv << 2) + sl;
    const float w = s_w[nl];
    const float4 a4 = pf[j];
    float acc;
    acc  = a4.x * __sinf(fmaf(w, m0, p0));
    acc += a4.y * __sinf(fmaf(w, m1, p1));
    acc += a4.z * __sinf(fmaf(w, m2, p2));
    acc += a4.w * __sinf(fmaf(w, m3, p3));
    acc += __shfl_xor(acc, 1);
    acc += __shfl_xor(acc, 2);
    acc += __shfl_xor(acc, 4);
    acc += __shfl_xor(acc, 8);
    if (hq == 0) yb[nl] = acc;
  }

#pragma unroll 4
  for (int i0 = PF * 24; i0 < CH; i0 += 24) {
    const int nl = i0 + (wv << 2) + sl;
    const float w = s_w[nl];
    const float4 a4 = ampb[(size_t)nl * (H / 4) + hq];
    float acc;
    acc  = a4.x * __sinf(fmaf(w, m0, p0));
    acc += a4.y * __sinf(fmaf(w, m1, p1));
    acc += a4.z * __sinf(fmaf(w, m2, p2));
    acc += a4.w * __sinf(fmaf(w, m3, p3));
    acc += __shfl_xor(acc, 1);
    acc += __shfl_xor(acc, 2);
    acc += __shfl_xor(acc, 4);
    acc += __shfl_xor(acc, 8);
    if (hq == 0) yb[nl] = acc;
  }

  // --- phase_out from the last chunk (double remainder) --------------------
  if (c == NCH - 1 && tid < H) {
    const double arg = s_last * (double)(tid + 1) + (double)phase[b * H + tid];
    double r = arg - TWO_PI_D * floor(arg * INV_TWO_PI_D);
    if (r < 0.0) r += TWO_PI_D;
    if (r >= TWO_PI_D) r -= TWO_PI_D;
    out[(size_t)B * N + b * H + tid] = (float)r;
  }
}

extern "C" void kernel_launch(void* const* d_in, const int* in_sizes, int n_in,
                              void* d_out, int out_size, void* d_ws, size_t ws_size,
                              hipStream_t stream) {
  const float* f0    = (const float*)d_in[0];   // (B, N)
  const float* amp   = (const float*)d_in[1];   // (B, N, H)
  const float* phase = (const float*)d_in[2];   // (B, H)
  float* out = (float*)d_out;                   // y (B*N) ++ phase_out (B*H)
  double* csum = (double*)d_ws;                 // B*NCH doubles = 8000 B

  k_chunk_sums<<<B * NCH, 256, 0, stream>>>(f0, csum);
  k_main<<<B * NCH, TM, 0, stream>>>(f0, amp, phase, csum, out);
}